// Round 21
// baseline (137.144 us; speedup 1.0000x reference)
//
#include <hip/hip_runtime.h>

// Problem constants (from reference)
#define NVN 65536
#define NCN 32768
#define NB 4
#define DIM 32
#define NE 262144
#define HID 40
#define MSGD 20
#define SLOT 40        // edge slots per check node (Poisson(8) max-deg ~25 << 40)
#define SOP 44         // padded sOut row stride in u16 (22 u32: gcd(22,32)=2 -> 2-way)

typedef unsigned short u16;
typedef unsigned int u32;
typedef __attribute__((ext_vector_type(8))) short bf16x8;
typedef __attribute__((ext_vector_type(4))) float f32x4;

// bf16 helpers (RNE pack, cheap unpack)
__device__ __forceinline__ u16 f2bf(float f) {
    u32 u = __float_as_uint(f);
    u += 0x7fff + ((u >> 16) & 1);
    return (u16)(u >> 16);
}
__device__ __forceinline__ float bflo(u32 u) { return __uint_as_float(u << 16); }
__device__ __forceinline__ float bfhi(u32 u) { return __uint_as_float(u & 0xffff0000u); }
__device__ __forceinline__ u32 pk2(float a, float b) {
    return (u32)f2bf(a) | ((u32)f2bf(b) << 16);
}

// ---------------- scatter_slot: STANDALONE again (diagnostic split of phase1) ----------
// r19/r20: phase1 stayed 80us through two traffic-reduction changes -> the unmeasured
// component (this scatter, unchanged since r13) is the prime suspect (~40us by
// cross-round subtraction). Separate dispatch so the profile attributes it.

__global__ __launch_bounds__(256) void scatter_slot(const int* __restrict__ to_x,
                                                    const int* __restrict__ from_x,
                                                    const int* __restrict__ to_z,
                                                    const int* __restrict__ from_z,
                                                    int* __restrict__ cnt_x,
                                                    int* __restrict__ cnt_z,
                                                    u16* __restrict__ ef_x,
                                                    u16* __restrict__ ef_z) {
    int bid = blockIdx.x;
    int e = (bid & 1023) * 256 + threadIdx.x;
    const int* t; const int* f; int* cnt; u16* ef;
    if (bid < 1024) { t = to_x; f = from_x; cnt = cnt_x; ef = ef_x; }
    else            { t = to_z; f = from_z; cnt = cnt_z; ef = ef_z; }
    int c = t[e];
    int pos = atomicAdd(&cnt[c], 1);
    if (pos < SLOT) ef[c * SLOT + pos] = (u16)f[e];
}

// ------- shared repack: sOut[128][SOP] bf16 -> 32 complete 320B lines at dst+v0*320 -------

__device__ __forceinline__ void repack_lines(int tid, const u16* sOut, u16* dst, int v0) {
    const u32* so = (const u32*)sOut;   // [128][22] packed col-pairs (padded)
    uint4* dp = (uint4*)((char*)dst + (size_t)v0 * 320);
    for (int i = tid; i < 640; i += 256) {
        int vloc = i / 20;
        int q0 = (i - vloc * 20) * 4;
        u32 vals[4];
#pragma unroll
        for (int j = 0; j < 4; j++) {
            int q = q0 + j;
            int ch, cp;
            if (q < 32)      { ch = q >> 2;        cp = (ch >> 2) * 10 + (q & 3); }
            else if (q < 64) { int t = q - 32; ch = t >> 2; cp = (ch >> 2) * 10 + 4 + (t & 3); }
            else             { int t = q - 64; ch = t >> 1; cp = (ch >> 2) * 10 + 8 + (t & 1); }
            int m = (ch & 3) * 32 + vloc;
            vals[j] = so[m * (SOP / 2) + cp];
        }
        dp[i] = make_uint4(vals[0], vals[1], vals[2], vals[3]);
    }
}

// ------- precompU both sides in ONE pass (h_from read/converted once; r20) -------

__device__ __forceinline__ void precompU_both_body(
        int bidl, int tid, const float* __restrict__ h_from,
        const float* __restrict__ Wx, const float* __restrict__ Wz,
        u16* __restrict__ dstx, u16* __restrict__ dstz,
        u16* sA, u16* sB, u16* sOut) {
    int v0 = bidl << 5;

    for (int i = tid; i < 2 * 1536; i += 256) {
        int sd = (i >= 1536);
        int idx = sd ? i - 1536 : i;
        int row = idx / 48, col = idx - row * 48;
        const float* W = sd ? Wz : Wx;
        sB[i] = (col < 40) ? f2bf(W[row * 40 + col]) : (u16)0;
    }
    {
        int r = tid >> 1, p = tid & 1;
        int b = r >> 5, vloc = r & 31;
        const float4* hp = (const float4*)(h_from + ((size_t)b * NVN + v0 + vloc) * DIM + p * 16);
        float4 x0 = hp[0], x1 = hp[1], x2 = hp[2], x3 = hp[3];
        uint4* d = (uint4*)(sA + r * 32 + p * 16);
        d[0] = make_uint4(pk2(x0.x, x0.y), pk2(x0.z, x0.w), pk2(x1.x, x1.y), pk2(x1.z, x1.w));
        d[1] = make_uint4(pk2(x2.x, x2.y), pk2(x2.z, x2.w), pk2(x3.x, x3.y), pk2(x3.z, x3.w));
    }
    __syncthreads();

    int wid = tid >> 6;
    int lane = tid & 63;
    int li = lane & 15;
    int lk = lane >> 4;

    bf16x8 bfr[2][3];
#pragma unroll
    for (int s = 0; s < 2; s++)
#pragma unroll
        for (int jt = 0; jt < 3; jt++) {
            bf16x8 v;
#pragma unroll
            for (int rr = 0; rr < 8; rr++)
                v[rr] = (short)sB[s * 1536 + (lk * 8 + rr) * 48 + jt * 16 + li];
            bfr[s][jt] = v;
        }
    bf16x8 a0 = *(const bf16x8*)(sA + (wid * 32 + li) * 32 + lk * 8);
    bf16x8 a1 = *(const bf16x8*)(sA + (wid * 32 + 16 + li) * 32 + lk * 8);

#pragma unroll
    for (int s = 0; s < 2; s++) {
        if (s) __syncthreads();   // prior repack's sOut reads complete before overwrite
#pragma unroll
        for (int rt = 0; rt < 2; rt++) {
            int rowloc = wid * 32 + rt * 16;
            bf16x8 a = rt ? a1 : a0;
#pragma unroll
            for (int jt = 0; jt < 3; jt++) {
                f32x4 acc = {0.f, 0.f, 0.f, 0.f};
                acc = __builtin_amdgcn_mfma_f32_16x16x32_bf16(a, bfr[s][jt], acc, 0, 0, 0);
                int col = jt * 16 + li;
                if (col < 40) {
#pragma unroll
                    for (int rr = 0; rr < 4; rr++)
                        sOut[(rowloc + lk * 4 + rr) * SOP + col] = f2bf(acc[rr]);
                }
            }
        }
        __syncthreads();
        repack_lines(tid, sOut, s ? dstz : dstx, v0);
    }
}

// ------- precompT body (single side per block) -------

__device__ __forceinline__ void precompT_body(
        int bidl, int tid,
        const float* __restrict__ h_x, const float* __restrict__ h_z,
        const float* __restrict__ W_x, const float* __restrict__ W_z,
        u16* __restrict__ dst_x, u16* __restrict__ dst_z,
        u16* sA, u16* sB, u16* sOut) {
    int bps = NCN >> 5;
    int side = bidl / bps;
    int v0 = (bidl - side * bps) << 5;

    const float* __restrict__ h = side ? h_z : h_x;
    const float* __restrict__ W = side ? W_z : W_x;
    u16* dst = side ? dst_z : dst_x;

    for (int i = tid; i < 1536; i += 256) {
        int row = i / 48, col = i - row * 48;
        sB[i] = (col < 40) ? f2bf(W[row * 40 + col]) : (u16)0;
    }
    {
        int r = tid >> 1, p = tid & 1;
        int b = r >> 5, vloc = r & 31;
        const float4* hp = (const float4*)(h + ((size_t)b * NCN + v0 + vloc) * DIM + p * 16);
        float4 x0 = hp[0], x1 = hp[1], x2 = hp[2], x3 = hp[3];
        uint4* d = (uint4*)(sA + r * 32 + p * 16);
        d[0] = make_uint4(pk2(x0.x, x0.y), pk2(x0.z, x0.w), pk2(x1.x, x1.y), pk2(x1.z, x1.w));
        d[1] = make_uint4(pk2(x2.x, x2.y), pk2(x2.z, x2.w), pk2(x3.x, x3.y), pk2(x3.z, x3.w));
    }
    __syncthreads();

    int wid = tid >> 6;
    int lane = tid & 63;
    int li = lane & 15;
    int lk = lane >> 4;

    bf16x8 bfr[3];
#pragma unroll
    for (int jt = 0; jt < 3; jt++) {
        bf16x8 v;
#pragma unroll
        for (int rr = 0; rr < 8; rr++)
            v[rr] = (short)sB[(lk * 8 + rr) * 48 + jt * 16 + li];
        bfr[jt] = v;
    }

#pragma unroll
    for (int rt = 0; rt < 2; rt++) {
        int rowloc = wid * 32 + rt * 16;
        bf16x8 a = *(const bf16x8*)(sA + (rowloc + li) * 32 + lk * 8);
#pragma unroll
        for (int jt = 0; jt < 3; jt++) {
            f32x4 acc = {0.f, 0.f, 0.f, 0.f};
            acc = __builtin_amdgcn_mfma_f32_16x16x32_bf16(a, bfr[jt], acc, 0, 0, 0);
            int col = jt * 16 + li;
            if (col < 40) {
#pragma unroll
                for (int rr = 0; rr < 4; rr++)
                    sOut[(rowloc + lk * 4 + rr) * SOP + col] = f2bf(acc[rr]);
            }
        }
    }
    __syncthreads();
    repack_lines(tid, sOut, dst, v0);
}

// ------- precomp_all: precompU(both) + precompT + prepW in one dispatch -------
//   [0,2048) precompU both sides (MFMA)   [2048,4096) precompT (MFMA)
//   [4096,4098) prepW

__global__ __launch_bounds__(256) void precomp_all(
        const float* __restrict__ h_from,
        const float* __restrict__ h_to_x, const float* __restrict__ h_to_z,
        const float* __restrict__ Wm1_x, const float* __restrict__ Wm1_z,
        const float* __restrict__ Wm2_x, const float* __restrict__ Wm2_z,
        const float* __restrict__ We1_x, const float* __restrict__ We1_z,
        const float* __restrict__ We2_x, const float* __restrict__ We2_z,
        u16* __restrict__ U2h_x, u16* __restrict__ U2h_z,
        u16* __restrict__ ts_x, u16* __restrict__ ts_z,
        u16* __restrict__ BW_x, u16* __restrict__ BW_z,
        u16* __restrict__ W2_x, u16* __restrict__ W2_z) {
    __shared__ __attribute__((aligned(16))) u16 sA[128 * 32];    //  8 KB
    __shared__ __attribute__((aligned(16))) u16 sB[2 * 1536];    //  6 KB
    __shared__ __attribute__((aligned(16))) u16 sOut[128 * SOP]; // 11 KB (padded)

    int bid = blockIdx.x;
    int tid = threadIdx.x;

    if (bid < 2048) {
        precompU_both_body(bid, tid, h_from, Wm1_x, Wm1_z,
                           U2h_x, U2h_z, sA, sB, sOut);
    } else if (bid < 4096) {
        precompT_body(bid - 2048, tid, h_to_x, h_to_z,
                      Wm1_x + DIM * HID, Wm1_z + DIM * HID,
                      ts_x, ts_z, sA, sB, sOut);
    } else {
        int side = bid - 4096;
        const float* Wm2 = side ? Wm2_z : Wm2_x;
        const float* We1 = side ? We1_z : We1_x;
        const float* We2 = side ? We2_z : We2_x;
        u16* BW = side ? BW_z : BW_x;
        u16* W2 = side ? W2_z : W2_x;
        for (int i = tid; i < 96 * 48; i += 256) {
            int row = i / 48, col = i % 48;
            float v = 0.f;
            if (col < 40) {
                if (row < 40) {
                    for (int k = 0; k < MSGD; k++) v += Wm2[row * MSGD + k] * We1[k * HID + col];
                } else if (row < 72) {
                    v = We1[(MSGD + row - 40) * HID + col];
                } else if (row == 72) {
                    v = We1[(MSGD + DIM) * HID + col];
                }
            }
            BW[i] = f2bf(v);
        }
        for (int i = tid; i < 64 * 32; i += 256) {
            int row = i / 32, col = i % 32;
            W2[i] = (row < 40) ? f2bf(We2[row * 32 + col]) : (u16)0;
        }
    }
}

// ------- aggA: pure gather+relu-sum, 16 lanes/node (edge-parity split; r19 WIN) -------

__global__ __launch_bounds__(256, 8) void aggA_kernel(
        const u16* __restrict__ U2h_x, const u16* __restrict__ U2h_z,
        u16* __restrict__ ts_x, u16* __restrict__ ts_z,
        const int* __restrict__ cnt_x, const int* __restrict__ cnt_z,
        const u16* __restrict__ ef_x, const u16* __restrict__ ef_z) {
    int side = blockIdx.x >> 11;
    const char* Ubase = (const char*)(side ? U2h_z : U2h_x);
    char* ts = (char*)(side ? ts_z : ts_x);
    const int* cnt = side ? cnt_z : cnt_x;
    const u16* ef = side ? ef_z : ef_x;

    int gt = (blockIdx.x & 2047) * 256 + threadIdx.x;
    int c = gt >> 4;
    int l16 = gt & 15;
    int chunk = l16 & 7;
    int par = l16 >> 3;
    int off16a = chunk * 16;
    int off8c = 256 + chunk * 8;

    char* tline = ts + (size_t)c * 320;
    uint4 T0 = *(const uint4*)(tline + off16a);
    uint4 T1 = *(const uint4*)(tline + off16a + 128);
    uint2 Tc = *(const uint2*)(tline + off8c);

    float s[20];
#pragma unroll
    for (int k = 0; k < 20; k++) s[k] = 0.f;

    int cn = cnt[c];
    cn = (cn < SLOT) ? cn : SLOT;
    const u16* efc = ef + c * SLOT;

    int vA = (par < cn) ? (int)efc[par] : 0;
#define ACC(su, aw, tw) { \
    s[su]     += fmaxf(bflo(aw) + bflo(tw), 0.f); \
    s[(su)+1] += fmaxf(bfhi(aw) + bfhi(tw), 0.f); }
    for (int i = par; i < cn; i += 2) {
        const char* pa = Ubase + (size_t)vA * 320;
        uint4 A0 = *(const uint4*)(pa + off16a);
        uint4 A1 = *(const uint4*)(pa + off16a + 128);
        uint2 A2 = *(const uint2*)(pa + off8c);
        vA = (i + 2 < cn) ? (int)efc[i + 2] : 0;
        ACC(0, A0.x, T0.x)  ACC(2, A0.y, T0.y)  ACC(4, A0.z, T0.z)  ACC(6, A0.w, T0.w)
        ACC(8, A1.x, T1.x)  ACC(10, A1.y, T1.y) ACC(12, A1.z, T1.z) ACC(14, A1.w, T1.w)
        ACC(16, A2.x, Tc.x) ACC(18, A2.y, Tc.y)
    }
#undef ACC

#pragma unroll
    for (int k = 0; k < 20; k++) s[k] += __shfl_xor(s[k], 8);

    if (par == 0) {
        u32 sp[10];
#pragma unroll
        for (int jq = 0; jq < 5; jq++) {
            sp[2 * jq]     = pk2(s[4 * jq + 0], s[4 * jq + 1]);
            sp[2 * jq + 1] = pk2(s[4 * jq + 2], s[4 * jq + 3]);
        }
        *(uint4*)(tline + off16a)       = make_uint4(sp[0], sp[1], sp[2], sp[3]);
        *(uint4*)(tline + off16a + 128) = make_uint4(sp[4], sp[5], sp[6], sp[7]);
        *(uint2*)(tline + off8c)        = make_uint2(sp[8], sp[9]);
    }
}

// ------- aggB_mfma: H = relu([s|X|lg] @ BW) ; out = H @ We2  (UNCHANGED, r16) -------

__global__ __launch_bounds__(256) void aggB_mfma(
        const u16* __restrict__ ts_x, const u16* __restrict__ ts_z,
        const float* __restrict__ h_to_x, const float* __restrict__ h_to_z,
        const float* __restrict__ logit_x, const float* __restrict__ logit_z,
        const u16* __restrict__ BW_x, const u16* __restrict__ BW_z,
        const u16* __restrict__ W2_x, const u16* __restrict__ W2_z,
        float* __restrict__ out) {
    __shared__ __attribute__((aligned(16))) u16 sA[128 * 96];   // 24,576 B
    __shared__ __attribute__((aligned(16))) u16 sH[128 * 64];   // 16,384 B
    __shared__ __attribute__((aligned(16))) u16 sBW[96 * 48];   //  9,216 B
    __shared__ __attribute__((aligned(16))) u16 sW2[64 * 32];   //  4,096 B

    int bid = blockIdx.x;
    int side = bid >> 10;
    const u16* ts = side ? ts_z : ts_x;
    const float* h_to = side ? h_to_z : h_to_x;
    const float* logit = side ? logit_z : logit_x;
    const u16* BWg = side ? BW_z : BW_x;
    const u16* W2g = side ? W2_z : W2_x;

    int tid = threadIdx.x;
    int rho0 = (bid & 1023) * 128;   // within-side row base
    int b = rho0 >> 15;              // uniform over the block
    int c0 = rho0 & 32767;

    for (int i = tid; i < (96 * 48) / 8; i += 256)
        ((uint4*)sBW)[i] = ((const uint4*)BWg)[i];
    if (tid < (64 * 32) / 8) ((uint4*)sW2)[tid] = ((const uint4*)W2g)[tid];

    {
        int r = tid >> 1;
        int part = tid & 1;
        int c = c0 + r;
        char* srow = (char*)sA + r * 192;
        if (part == 0) {
            const char* tr = (const char*)ts + (size_t)c * 320;
            uint4 p0 = *(const uint4*)(tr + b * 16);
            uint4 p1 = *(const uint4*)(tr + 128 + b * 16);
            uint2 p2 = *(const uint2*)(tr + 256 + b * 8);
            uint4 p3 = *(const uint4*)(tr + (4 + b) * 16);
            uint4 p4 = *(const uint4*)(tr + 128 + (4 + b) * 16);
            uint2 p5 = *(const uint2*)(tr + 256 + (4 + b) * 8);
            *(uint4*)(srow + 0)  = p0;
            *(uint4*)(srow + 16) = p1;
            *(uint2*)(srow + 32) = p2;
            *(uint2*)(srow + 40) = make_uint2(p3.x, p3.y);
            *(uint2*)(srow + 48) = make_uint2(p3.z, p3.w);
            *(uint2*)(srow + 56) = make_uint2(p4.x, p4.y);
            *(uint2*)(srow + 64) = make_uint2(p4.z, p4.w);
            *(uint2*)(srow + 72) = p5;
            char* hrow = (char*)sH + r * 128;
            *(uint4*)(hrow + 96)  = make_uint4(0, 0, 0, 0);
            *(uint4*)(hrow + 112) = make_uint4(0, 0, 0, 0);
        } else {
            const float4* xp = (const float4*)(h_to + ((size_t)b * NCN + c) * DIM);
#pragma unroll
            for (int q = 0; q < 4; q++) {
                float4 x0 = xp[2 * q], x1 = xp[2 * q + 1];
                *(uint4*)(srow + 80 + q * 16) =
                    make_uint4(pk2(x0.x, x0.y), pk2(x0.z, x0.w),
                               pk2(x1.x, x1.y), pk2(x1.z, x1.w));
            }
            float lg = logit[(size_t)b * NCN + c];
            *(uint4*)(srow + 144) = make_uint4((u32)f2bf(lg), 0, 0, 0);
            *(uint4*)(srow + 160) = make_uint4(0, 0, 0, 0);
            *(uint4*)(srow + 176) = make_uint4(0, 0, 0, 0);
        }
    }
    __syncthreads();

    int wid = tid >> 6;
    int lane = tid & 63;
    int li = lane & 15;
    int lk = lane >> 4;
    int rowq = lk * 4;

    bf16x8 bA[3][3];
#pragma unroll
    for (int jt = 0; jt < 3; jt++)
#pragma unroll
        for (int ks = 0; ks < 3; ks++) {
            bf16x8 v;
#pragma unroll
            for (int rr = 0; rr < 8; rr++)
                v[rr] = (short)sBW[(ks * 32 + lk * 8 + rr) * 48 + jt * 16 + li];
            bA[jt][ks] = v;
        }

#pragma unroll
    for (int rt = 0; rt < 2; rt++) {
        int rowloc = wid * 32 + rt * 16;
        const char* abase = (const char*)sA + (rowloc + li) * 192 + lk * 16;
        bf16x8 a0 = *(const bf16x8*)(abase);
        bf16x8 a1 = *(const bf16x8*)(abase + 64);
        bf16x8 a2 = *(const bf16x8*)(abase + 128);
#pragma unroll
        for (int jt = 0; jt < 3; jt++) {
            f32x4 acc = {0.f, 0.f, 0.f, 0.f};
            acc = __builtin_amdgcn_mfma_f32_16x16x32_bf16(a0, bA[jt][0], acc, 0, 0, 0);
            acc = __builtin_amdgcn_mfma_f32_16x16x32_bf16(a1, bA[jt][1], acc, 0, 0, 0);
            acc = __builtin_amdgcn_mfma_f32_16x16x32_bf16(a2, bA[jt][2], acc, 0, 0, 0);
#pragma unroll
            for (int rr = 0; rr < 4; rr++)
                sH[(rowloc + rowq + rr) * 64 + jt * 16 + li] = f2bf(fmaxf(acc[rr], 0.f));
        }
    }
    __syncthreads();

    bf16x8 bB[2][2];
#pragma unroll
    for (int jt = 0; jt < 2; jt++)
#pragma unroll
        for (int ks = 0; ks < 2; ks++) {
            bf16x8 v;
#pragma unroll
            for (int rr = 0; rr < 8; rr++)
                v[rr] = (short)sW2[(ks * 32 + lk * 8 + rr) * 32 + jt * 16 + li];
            bB[jt][ks] = v;
        }

    size_t rowg0 = (size_t)bid * 128;
#pragma unroll
    for (int rt = 0; rt < 2; rt++) {
        int rowloc = wid * 32 + rt * 16;
        const char* hbase = (const char*)sH + (rowloc + li) * 128 + lk * 16;
        bf16x8 h0 = *(const bf16x8*)(hbase);
        bf16x8 h1 = *(const bf16x8*)(hbase + 64);
#pragma unroll
        for (int jt = 0; jt < 2; jt++) {
            f32x4 acc = {0.f, 0.f, 0.f, 0.f};
            acc = __builtin_amdgcn_mfma_f32_16x16x32_bf16(h0, bB[jt][0], acc, 0, 0, 0);
            acc = __builtin_amdgcn_mfma_f32_16x16x32_bf16(h1, bB[jt][1], acc, 0, 0, 0);
#pragma unroll
            for (int rr = 0; rr < 4; rr++)
                out[(rowg0 + rowloc + rowq + rr) * 32 + jt * 16 + li] = acc[rr];
        }
    }
}

// ---------------- host ----------------

extern "C" void kernel_launch(void* const* d_in, const int* in_sizes, int n_in,
                              void* d_out, int out_size, void* d_ws, size_t ws_size,
                              hipStream_t stream) {
    const float* h_from   = (const float*)d_in[0];
    const float* h_to_x   = (const float*)d_in[1];
    const float* h_to_z   = (const float*)d_in[2];
    const float* hx_logit = (const float*)d_in[3];
    const float* hz_logit = (const float*)d_in[4];
    const int*   from_x   = (const int*)d_in[5];
    const int*   to_x     = (const int*)d_in[6];
    const int*   from_z   = (const int*)d_in[7];
    const int*   to_z     = (const int*)d_in[8];
    const float* Wm1_x    = (const float*)d_in[9];
    const float* Wm2_x    = (const float*)d_in[10];
    const float* Wm1_z    = (const float*)d_in[11];
    const float* Wm2_z    = (const float*)d_in[12];
    const float* We1_x    = (const float*)d_in[13];
    const float* We2_x    = (const float*)d_in[14];
    const float* We1_z    = (const float*)d_in[15];
    const float* We2_z    = (const float*)d_in[16];

    // Workspace layout (bytes), end = 68,446,208 (<= proven 85,328,128 budget)
    char* ws = (char*)d_ws;
    u16* U2h_x = (u16*)(ws);                       // 65536*320 = 20,971,520
    u16* U2h_z = (u16*)(ws + 20971520);            // 20,971,520
    u16* ts_x  = (u16*)(ws + 41943040);            // 32768*320 = 10,485,760 (T, then s)
    u16* ts_z  = (u16*)(ws + 52428800);            // 10,485,760
    u16* ef_x  = (u16*)(ws + 62914560);            // 32768*40*2 = 2,621,440
    u16* ef_z  = (u16*)(ws + 65536000);            // 2,621,440
    int* cnt_x = (int*)(ws + 68157440);            // 131,072
    int* cnt_z = (int*)(ws + 68288512);            // 131,072
    u16* BW_x  = (u16*)(ws + 68419584);            // 96*48*2 = 9,216
    u16* BW_z  = (u16*)(ws + 68428800);            // 9,216
    u16* W2_x  = (u16*)(ws + 68438016);            // 64*32*2 = 4,096
    u16* W2_z  = (u16*)(ws + 68442112);            // 4,096
    float* out = (float*)d_out;

    hipMemsetAsync(ws + 68157440, 0, 262144, stream);  // zero cnt_x + cnt_z
    scatter_slot<<<2048, 256, 0, stream>>>(to_x, from_x, to_z, from_z,
                                           cnt_x, cnt_z, ef_x, ef_z);
    precomp_all<<<4098, 256, 0, stream>>>(h_from, h_to_x, h_to_z,
                                          Wm1_x, Wm1_z, Wm2_x, Wm2_z,
                                          We1_x, We1_z, We2_x, We2_z,
                                          U2h_x, U2h_z, ts_x, ts_z,
                                          BW_x, BW_z, W2_x, W2_z);
    aggA_kernel<<<4096, 256, 0, stream>>>(U2h_x, U2h_z, ts_x, ts_z,
                                          cnt_x, cnt_z, ef_x, ef_z);
    aggB_mfma<<<2048, 256, 0, stream>>>(ts_x, ts_z, h_to_x, h_to_z,
                                        hx_logit, hz_logit,
                                        BW_x, BW_z, W2_x, W2_z, out);
}

// Round 22
// 126.557 us; speedup vs baseline: 1.0837x; 1.0837x over previous
//
#include <hip/hip_runtime.h>
#include <hip/hip_bf16.h>

// Problem constants (from reference)
#define NVN 65536
#define NCN 32768
#define NB 4
#define DIM 32
#define NE 262144
#define HID 40
#define MSGD 20
#define SLOT 40        // edge slots per check node (Poisson(8) max-deg ~25 << 40)

typedef unsigned short u16;
typedef unsigned int u32;
typedef __attribute__((ext_vector_type(8))) short bf16x8;
typedef __attribute__((ext_vector_type(4))) float f32x4;

// bf16 helpers — HW cvt instructions via HIP intrinsics (r21: hand-rolled RNE bit
// math cost ~5 VALU/value; ~400 VALU instrs/thread in precomp was the VALUBusy bulk).
__device__ __forceinline__ u16 f2bf(float f) {
    __hip_bfloat16 h = __float2bfloat16(f);
    return *reinterpret_cast<u16*>(&h);
}
__device__ __forceinline__ u32 pk2(float a, float b) {
    __hip_bfloat162 h = __float22bfloat162_rn(float2{a, b});
    return *reinterpret_cast<u32*>(&h);
}
__device__ __forceinline__ float bflo(u32 u) { return __uint_as_float(u << 16); }
__device__ __forceinline__ float bfhi(u32 u) { return __uint_as_float(u & 0xffff0000u); }

// ------- shared repack: sOut[128][40] bf16 -> 32 complete 320B lines at dst+v0*320 -------

__device__ __forceinline__ void repack_lines(int tid, const u16* sOut, u16* dst, int v0) {
    const u32* so = (const u32*)sOut;   // [128][20] packed col-pairs
    uint4* dp = (uint4*)((char*)dst + (size_t)v0 * 320);
    for (int i = tid; i < 640; i += 256) {
        int vloc = i / 20;
        int q0 = (i - vloc * 20) * 4;
        u32 vals[4];
#pragma unroll
        for (int j = 0; j < 4; j++) {
            int q = q0 + j;
            int ch, cp;
            if (q < 32)      { ch = q >> 2;        cp = (ch >> 2) * 10 + (q & 3); }
            else if (q < 64) { int t = q - 32; ch = t >> 2; cp = (ch >> 2) * 10 + 4 + (t & 3); }
            else             { int t = q - 64; ch = t >> 1; cp = (ch >> 2) * 10 + 8 + (t & 1); }
            int m = (ch & 3) * 32 + vloc;
            vals[j] = so[m * 20 + cp];
        }
        dp[i] = make_uint4(vals[0], vals[1], vals[2], vals[3]);
    }
}

// ------- precompU both sides in ONE pass (h_from read/converted once; r20) -------

__device__ __forceinline__ void precompU_both_body(
        int bidl, int tid, const float* __restrict__ h_from,
        const float* __restrict__ Wx, const float* __restrict__ Wz,
        u16* __restrict__ dstx, u16* __restrict__ dstz,
        u16* sA, u16* sB, u16* sOut) {
    int v0 = bidl << 5;

    for (int i = tid; i < 2 * 1536; i += 256) {
        int sd = (i >= 1536);
        int idx = sd ? i - 1536 : i;
        int row = idx / 48, col = idx - row * 48;
        const float* W = sd ? Wz : Wx;
        sB[i] = (col < 40) ? f2bf(W[row * 40 + col]) : (u16)0;
    }
    {
        int r = tid >> 1, p = tid & 1;
        int b = r >> 5, vloc = r & 31;
        const float4* hp = (const float4*)(h_from + ((size_t)b * NVN + v0 + vloc) * DIM + p * 16);
        float4 x0 = hp[0], x1 = hp[1], x2 = hp[2], x3 = hp[3];
        uint4* d = (uint4*)(sA + r * 32 + p * 16);
        d[0] = make_uint4(pk2(x0.x, x0.y), pk2(x0.z, x0.w), pk2(x1.x, x1.y), pk2(x1.z, x1.w));
        d[1] = make_uint4(pk2(x2.x, x2.y), pk2(x2.z, x2.w), pk2(x3.x, x3.y), pk2(x3.z, x3.w));
    }
    __syncthreads();

    int wid = tid >> 6;
    int lane = tid & 63;
    int li = lane & 15;
    int lk = lane >> 4;

    bf16x8 bfr[2][3];
#pragma unroll
    for (int s = 0; s < 2; s++)
#pragma unroll
        for (int jt = 0; jt < 3; jt++) {
            bf16x8 v;
#pragma unroll
            for (int rr = 0; rr < 8; rr++)
                v[rr] = (short)sB[s * 1536 + (lk * 8 + rr) * 48 + jt * 16 + li];
            bfr[s][jt] = v;
        }
    bf16x8 a0 = *(const bf16x8*)(sA + (wid * 32 + li) * 32 + lk * 8);
    bf16x8 a1 = *(const bf16x8*)(sA + (wid * 32 + 16 + li) * 32 + lk * 8);

#pragma unroll
    for (int s = 0; s < 2; s++) {
        if (s) __syncthreads();   // prior repack's sOut reads complete before overwrite
#pragma unroll
        for (int rt = 0; rt < 2; rt++) {
            int rowloc = wid * 32 + rt * 16;
            bf16x8 a = rt ? a1 : a0;
#pragma unroll
            for (int jt = 0; jt < 3; jt++) {
                f32x4 acc = {0.f, 0.f, 0.f, 0.f};
                acc = __builtin_amdgcn_mfma_f32_16x16x32_bf16(a, bfr[s][jt], acc, 0, 0, 0);
                int col = jt * 16 + li;
                if (col < 40) {
#pragma unroll
                    for (int rr = 0; rr < 4; rr++)
                        sOut[(rowloc + lk * 4 + rr) * 40 + col] = f2bf(acc[rr]);
                }
            }
        }
        __syncthreads();
        repack_lines(tid, sOut, s ? dstz : dstx, v0);
    }
}

// ------- precompT body (single side per block) -------

__device__ __forceinline__ void precompT_body(
        int bidl, int tid,
        const float* __restrict__ h_x, const float* __restrict__ h_z,
        const float* __restrict__ W_x, const float* __restrict__ W_z,
        u16* __restrict__ dst_x, u16* __restrict__ dst_z,
        u16* sA, u16* sB, u16* sOut) {
    int bps = NCN >> 5;
    int side = bidl / bps;
    int v0 = (bidl - side * bps) << 5;

    const float* __restrict__ h = side ? h_z : h_x;
    const float* __restrict__ W = side ? W_z : W_x;
    u16* dst = side ? dst_z : dst_x;

    for (int i = tid; i < 1536; i += 256) {
        int row = i / 48, col = i - row * 48;
        sB[i] = (col < 40) ? f2bf(W[row * 40 + col]) : (u16)0;
    }
    {
        int r = tid >> 1, p = tid & 1;
        int b = r >> 5, vloc = r & 31;
        const float4* hp = (const float4*)(h + ((size_t)b * NCN + v0 + vloc) * DIM + p * 16);
        float4 x0 = hp[0], x1 = hp[1], x2 = hp[2], x3 = hp[3];
        uint4* d = (uint4*)(sA + r * 32 + p * 16);
        d[0] = make_uint4(pk2(x0.x, x0.y), pk2(x0.z, x0.w), pk2(x1.x, x1.y), pk2(x1.z, x1.w));
        d[1] = make_uint4(pk2(x2.x, x2.y), pk2(x2.z, x2.w), pk2(x3.x, x3.y), pk2(x3.z, x3.w));
    }
    __syncthreads();

    int wid = tid >> 6;
    int lane = tid & 63;
    int li = lane & 15;
    int lk = lane >> 4;

    bf16x8 bfr[3];
#pragma unroll
    for (int jt = 0; jt < 3; jt++) {
        bf16x8 v;
#pragma unroll
        for (int rr = 0; rr < 8; rr++)
            v[rr] = (short)sB[(lk * 8 + rr) * 48 + jt * 16 + li];
        bfr[jt] = v;
    }

#pragma unroll
    for (int rt = 0; rt < 2; rt++) {
        int rowloc = wid * 32 + rt * 16;
        bf16x8 a = *(const bf16x8*)(sA + (rowloc + li) * 32 + lk * 8);
#pragma unroll
        for (int jt = 0; jt < 3; jt++) {
            f32x4 acc = {0.f, 0.f, 0.f, 0.f};
            acc = __builtin_amdgcn_mfma_f32_16x16x32_bf16(a, bfr[jt], acc, 0, 0, 0);
            int col = jt * 16 + li;
            if (col < 40) {
#pragma unroll
                for (int rr = 0; rr < 4; rr++)
                    sOut[(rowloc + lk * 4 + rr) * 40 + col] = f2bf(acc[rr]);
            }
        }
    }
    __syncthreads();
    repack_lines(tid, sOut, dst, v0);
}

// ------- phase1: scatter + precompU(both) + precompT + prepW in ONE dispatch (r20) -------
//   [0,2048)  scatter (atomic)   [2048,4096) precompU both sides (MFMA)
//   [4096,6144) precompT (MFMA)  [6144,6146) prepW

__global__ __launch_bounds__(256) void phase1(
        const int* __restrict__ to_x, const int* __restrict__ from_x,
        const int* __restrict__ to_z, const int* __restrict__ from_z,
        int* __restrict__ cnt_x, int* __restrict__ cnt_z,
        u16* __restrict__ ef_x, u16* __restrict__ ef_z,
        const float* __restrict__ h_from,
        const float* __restrict__ h_to_x, const float* __restrict__ h_to_z,
        const float* __restrict__ Wm1_x, const float* __restrict__ Wm1_z,
        const float* __restrict__ Wm2_x, const float* __restrict__ Wm2_z,
        const float* __restrict__ We1_x, const float* __restrict__ We1_z,
        const float* __restrict__ We2_x, const float* __restrict__ We2_z,
        u16* __restrict__ U2h_x, u16* __restrict__ U2h_z,
        u16* __restrict__ ts_x, u16* __restrict__ ts_z,
        u16* __restrict__ BW_x, u16* __restrict__ BW_z,
        u16* __restrict__ W2_x, u16* __restrict__ W2_z) {
    __shared__ __attribute__((aligned(16))) u16 sA[128 * 32];   //  8 KB
    __shared__ __attribute__((aligned(16))) u16 sB[2 * 1536];   //  6 KB
    __shared__ __attribute__((aligned(16))) u16 sOut[128 * 40]; // 10 KB

    int bid = blockIdx.x;
    int tid = threadIdx.x;

    if (bid < 2048) {
        int e = (bid & 1023) * 256 + tid;
        const int* t; const int* f; int* cnt; u16* ef;
        if (bid < 1024) { t = to_x; f = from_x; cnt = cnt_x; ef = ef_x; }
        else            { t = to_z; f = from_z; cnt = cnt_z; ef = ef_z; }
        int c = t[e];
        int pos = atomicAdd(&cnt[c], 1);
        if (pos < SLOT) ef[c * SLOT + pos] = (u16)f[e];
    } else if (bid < 4096) {
        precompU_both_body(bid - 2048, tid, h_from, Wm1_x, Wm1_z,
                           U2h_x, U2h_z, sA, sB, sOut);
    } else if (bid < 6144) {
        precompT_body(bid - 4096, tid, h_to_x, h_to_z,
                      Wm1_x + DIM * HID, Wm1_z + DIM * HID,
                      ts_x, ts_z, sA, sB, sOut);
    } else {
        int side = bid - 6144;
        const float* Wm2 = side ? Wm2_z : Wm2_x;
        const float* We1 = side ? We1_z : We1_x;
        const float* We2 = side ? We2_z : We2_x;
        u16* BW = side ? BW_z : BW_x;
        u16* W2 = side ? W2_z : W2_x;
        for (int i = tid; i < 96 * 48; i += 256) {
            int row = i / 48, col = i % 48;
            float v = 0.f;
            if (col < 40) {
                if (row < 40) {
                    for (int k = 0; k < MSGD; k++) v += Wm2[row * MSGD + k] * We1[k * HID + col];
                } else if (row < 72) {
                    v = We1[(MSGD + row - 40) * HID + col];
                } else if (row == 72) {
                    v = We1[(MSGD + DIM) * HID + col];
                }
            }
            BW[i] = f2bf(v);
        }
        for (int i = tid; i < 64 * 32; i += 256) {
            int row = i / 32, col = i % 32;
            W2[i] = (row < 40) ? f2bf(We2[row * 32 + col]) : (u16)0;
        }
    }
}

// ------- aggA: pure gather+relu-sum, 16 lanes/node (edge-parity split; r19 WIN) -------

__global__ __launch_bounds__(256, 8) void aggA_kernel(
        const u16* __restrict__ U2h_x, const u16* __restrict__ U2h_z,
        u16* __restrict__ ts_x, u16* __restrict__ ts_z,
        const int* __restrict__ cnt_x, const int* __restrict__ cnt_z,
        const u16* __restrict__ ef_x, const u16* __restrict__ ef_z) {
    int side = blockIdx.x >> 11;
    const char* Ubase = (const char*)(side ? U2h_z : U2h_x);
    char* ts = (char*)(side ? ts_z : ts_x);
    const int* cnt = side ? cnt_z : cnt_x;
    const u16* ef = side ? ef_z : ef_x;

    int gt = (blockIdx.x & 2047) * 256 + threadIdx.x;
    int c = gt >> 4;
    int l16 = gt & 15;
    int chunk = l16 & 7;
    int par = l16 >> 3;
    int off16a = chunk * 16;
    int off8c = 256 + chunk * 8;

    char* tline = ts + (size_t)c * 320;
    uint4 T0 = *(const uint4*)(tline + off16a);
    uint4 T1 = *(const uint4*)(tline + off16a + 128);
    uint2 Tc = *(const uint2*)(tline + off8c);

    float s[20];
#pragma unroll
    for (int k = 0; k < 20; k++) s[k] = 0.f;

    int cn = cnt[c];
    cn = (cn < SLOT) ? cn : SLOT;
    const u16* efc = ef + c * SLOT;

    int vA = (par < cn) ? (int)efc[par] : 0;
#define ACC(su, aw, tw) { \
    s[su]     += fmaxf(bflo(aw) + bflo(tw), 0.f); \
    s[(su)+1] += fmaxf(bfhi(aw) + bfhi(tw), 0.f); }
    for (int i = par; i < cn; i += 2) {
        const char* pa = Ubase + (size_t)vA * 320;
        uint4 A0 = *(const uint4*)(pa + off16a);
        uint4 A1 = *(const uint4*)(pa + off16a + 128);
        uint2 A2 = *(const uint2*)(pa + off8c);
        vA = (i + 2 < cn) ? (int)efc[i + 2] : 0;
        ACC(0, A0.x, T0.x)  ACC(2, A0.y, T0.y)  ACC(4, A0.z, T0.z)  ACC(6, A0.w, T0.w)
        ACC(8, A1.x, T1.x)  ACC(10, A1.y, T1.y) ACC(12, A1.z, T1.z) ACC(14, A1.w, T1.w)
        ACC(16, A2.x, Tc.x) ACC(18, A2.y, Tc.y)
    }
#undef ACC

#pragma unroll
    for (int k = 0; k < 20; k++) s[k] += __shfl_xor(s[k], 8);

    if (par == 0) {
        u32 sp[10];
#pragma unroll
        for (int jq = 0; jq < 5; jq++) {
            sp[2 * jq]     = pk2(s[4 * jq + 0], s[4 * jq + 1]);
            sp[2 * jq + 1] = pk2(s[4 * jq + 2], s[4 * jq + 3]);
        }
        *(uint4*)(tline + off16a)       = make_uint4(sp[0], sp[1], sp[2], sp[3]);
        *(uint4*)(tline + off16a + 128) = make_uint4(sp[4], sp[5], sp[6], sp[7]);
        *(uint2*)(tline + off8c)        = make_uint2(sp[8], sp[9]);
    }
}

// ------- aggB_mfma: H = relu([s|X|lg] @ BW) ; out = H @ We2  (UNCHANGED, r16) -------

__global__ __launch_bounds__(256) void aggB_mfma(
        const u16* __restrict__ ts_x, const u16* __restrict__ ts_z,
        const float* __restrict__ h_to_x, const float* __restrict__ h_to_z,
        const float* __restrict__ logit_x, const float* __restrict__ logit_z,
        const u16* __restrict__ BW_x, const u16* __restrict__ BW_z,
        const u16* __restrict__ W2_x, const u16* __restrict__ W2_z,
        float* __restrict__ out) {
    __shared__ __attribute__((aligned(16))) u16 sA[128 * 96];   // 24,576 B
    __shared__ __attribute__((aligned(16))) u16 sH[128 * 64];   // 16,384 B
    __shared__ __attribute__((aligned(16))) u16 sBW[96 * 48];   //  9,216 B
    __shared__ __attribute__((aligned(16))) u16 sW2[64 * 32];   //  4,096 B

    int bid = blockIdx.x;
    int side = bid >> 10;
    const u16* ts = side ? ts_z : ts_x;
    const float* h_to = side ? h_to_z : h_to_x;
    const float* logit = side ? logit_z : logit_x;
    const u16* BWg = side ? BW_z : BW_x;
    const u16* W2g = side ? W2_z : W2_x;

    int tid = threadIdx.x;
    int rho0 = (bid & 1023) * 128;   // within-side row base
    int b = rho0 >> 15;              // uniform over the block
    int c0 = rho0 & 32767;

    for (int i = tid; i < (96 * 48) / 8; i += 256)
        ((uint4*)sBW)[i] = ((const uint4*)BWg)[i];
    if (tid < (64 * 32) / 8) ((uint4*)sW2)[tid] = ((const uint4*)W2g)[tid];

    {
        int r = tid >> 1;
        int part = tid & 1;
        int c = c0 + r;
        char* srow = (char*)sA + r * 192;
        if (part == 0) {
            const char* tr = (const char*)ts + (size_t)c * 320;
            uint4 p0 = *(const uint4*)(tr + b * 16);
            uint4 p1 = *(const uint4*)(tr + 128 + b * 16);
            uint2 p2 = *(const uint2*)(tr + 256 + b * 8);
            uint4 p3 = *(const uint4*)(tr + (4 + b) * 16);
            uint4 p4 = *(const uint4*)(tr + 128 + (4 + b) * 16);
            uint2 p5 = *(const uint2*)(tr + 256 + (4 + b) * 8);
            *(uint4*)(srow + 0)  = p0;
            *(uint4*)(srow + 16) = p1;
            *(uint2*)(srow + 32) = p2;
            *(uint2*)(srow + 40) = make_uint2(p3.x, p3.y);
            *(uint2*)(srow + 48) = make_uint2(p3.z, p3.w);
            *(uint2*)(srow + 56) = make_uint2(p4.x, p4.y);
            *(uint2*)(srow + 64) = make_uint2(p4.z, p4.w);
            *(uint2*)(srow + 72) = p5;
            char* hrow = (char*)sH + r * 128;
            *(uint4*)(hrow + 96)  = make_uint4(0, 0, 0, 0);
            *(uint4*)(hrow + 112) = make_uint4(0, 0, 0, 0);
        } else {
            const float4* xp = (const float4*)(h_to + ((size_t)b * NCN + c) * DIM);
#pragma unroll
            for (int q = 0; q < 4; q++) {
                float4 x0 = xp[2 * q], x1 = xp[2 * q + 1];
                *(uint4*)(srow + 80 + q * 16) =
                    make_uint4(pk2(x0.x, x0.y), pk2(x0.z, x0.w),
                               pk2(x1.x, x1.y), pk2(x1.z, x1.w));
            }
            float lg = logit[(size_t)b * NCN + c];
            *(uint4*)(srow + 144) = make_uint4((u32)f2bf(lg), 0, 0, 0);
            *(uint4*)(srow + 160) = make_uint4(0, 0, 0, 0);
            *(uint4*)(srow + 176) = make_uint4(0, 0, 0, 0);
        }
    }
    __syncthreads();

    int wid = tid >> 6;
    int lane = tid & 63;
    int li = lane & 15;
    int lk = lane >> 4;
    int rowq = lk * 4;

    bf16x8 bA[3][3];
#pragma unroll
    for (int jt = 0; jt < 3; jt++)
#pragma unroll
        for (int ks = 0; ks < 3; ks++) {
            bf16x8 v;
#pragma unroll
            for (int rr = 0; rr < 8; rr++)
                v[rr] = (short)sBW[(ks * 32 + lk * 8 + rr) * 48 + jt * 16 + li];
            bA[jt][ks] = v;
        }

#pragma unroll
    for (int rt = 0; rt < 2; rt++) {
        int rowloc = wid * 32 + rt * 16;
        const char* abase = (const char*)sA + (rowloc + li) * 192 + lk * 16;
        bf16x8 a0 = *(const bf16x8*)(abase);
        bf16x8 a1 = *(const bf16x8*)(abase + 64);
        bf16x8 a2 = *(const bf16x8*)(abase + 128);
#pragma unroll
        for (int jt = 0; jt < 3; jt++) {
            f32x4 acc = {0.f, 0.f, 0.f, 0.f};
            acc = __builtin_amdgcn_mfma_f32_16x16x32_bf16(a0, bA[jt][0], acc, 0, 0, 0);
            acc = __builtin_amdgcn_mfma_f32_16x16x32_bf16(a1, bA[jt][1], acc, 0, 0, 0);
            acc = __builtin_amdgcn_mfma_f32_16x16x32_bf16(a2, bA[jt][2], acc, 0, 0, 0);
#pragma unroll
            for (int rr = 0; rr < 4; rr++)
                sH[(rowloc + rowq + rr) * 64 + jt * 16 + li] = f2bf(fmaxf(acc[rr], 0.f));
        }
    }
    __syncthreads();

    bf16x8 bB[2][2];
#pragma unroll
    for (int jt = 0; jt < 2; jt++)
#pragma unroll
        for (int ks = 0; ks < 2; ks++) {
            bf16x8 v;
#pragma unroll
            for (int rr = 0; rr < 8; rr++)
                v[rr] = (short)sW2[(ks * 32 + lk * 8 + rr) * 32 + jt * 16 + li];
            bB[jt][ks] = v;
        }

    size_t rowg0 = (size_t)bid * 128;
#pragma unroll
    for (int rt = 0; rt < 2; rt++) {
        int rowloc = wid * 32 + rt * 16;
        const char* hbase = (const char*)sH + (rowloc + li) * 128 + lk * 16;
        bf16x8 h0 = *(const bf16x8*)(hbase);
        bf16x8 h1 = *(const bf16x8*)(hbase + 64);
#pragma unroll
        for (int jt = 0; jt < 2; jt++) {
            f32x4 acc = {0.f, 0.f, 0.f, 0.f};
            acc = __builtin_amdgcn_mfma_f32_16x16x32_bf16(h0, bB[jt][0], acc, 0, 0, 0);
            acc = __builtin_amdgcn_mfma_f32_16x16x32_bf16(h1, bB[jt][1], acc, 0, 0, 0);
#pragma unroll
            for (int rr = 0; rr < 4; rr++)
                out[(rowg0 + rowloc + rowq + rr) * 32 + jt * 16 + li] = acc[rr];
        }
    }
}

// ---------------- host ----------------

extern "C" void kernel_launch(void* const* d_in, const int* in_sizes, int n_in,
                              void* d_out, int out_size, void* d_ws, size_t ws_size,
                              hipStream_t stream) {
    const float* h_from   = (const float*)d_in[0];
    const float* h_to_x   = (const float*)d_in[1];
    const float* h_to_z   = (const float*)d_in[2];
    const float* hx_logit = (const float*)d_in[3];
    const float* hz_logit = (const float*)d_in[4];
    const int*   from_x   = (const int*)d_in[5];
    const int*   to_x     = (const int*)d_in[6];
    const int*   from_z   = (const int*)d_in[7];
    const int*   to_z     = (const int*)d_in[8];
    const float* Wm1_x    = (const float*)d_in[9];
    const float* Wm2_x    = (const float*)d_in[10];
    const float* Wm1_z    = (const float*)d_in[11];
    const float* Wm2_z    = (const float*)d_in[12];
    const float* We1_x    = (const float*)d_in[13];
    const float* We2_x    = (const float*)d_in[14];
    const float* We1_z    = (const float*)d_in[15];
    const float* We2_z    = (const float*)d_in[16];

    // Workspace layout (bytes), end = 68,446,208 (<= proven 85,328,128 budget)
    char* ws = (char*)d_ws;
    u16* U2h_x = (u16*)(ws);                       // 65536*320 = 20,971,520
    u16* U2h_z = (u16*)(ws + 20971520);            // 20,971,520
    u16* ts_x  = (u16*)(ws + 41943040);            // 32768*320 = 10,485,760 (T, then s)
    u16* ts_z  = (u16*)(ws + 52428800);            // 10,485,760
    u16* ef_x  = (u16*)(ws + 62914560);            // 32768*40*2 = 2,621,440
    u16* ef_z  = (u16*)(ws + 65536000);            // 2,621,440
    int* cnt_x = (int*)(ws + 68157440);            // 131,072
    int* cnt_z = (int*)(ws + 68288512);            // 131,072
    u16* BW_x  = (u16*)(ws + 68419584);            // 96*48*2 = 9,216
    u16* BW_z  = (u16*)(ws + 68428800);            // 9,216
    u16* W2_x  = (u16*)(ws + 68438016);            // 64*32*2 = 4,096
    u16* W2_z  = (u16*)(ws + 68442112);            // 4,096
    float* out = (float*)d_out;

    hipMemsetAsync(ws + 68157440, 0, 262144, stream);  // zero cnt_x + cnt_z
    phase1<<<6146, 256, 0, stream>>>(to_x, from_x, to_z, from_z,
                                     cnt_x, cnt_z, ef_x, ef_z,
                                     h_from, h_to_x, h_to_z,
                                     Wm1_x, Wm1_z, Wm2_x, Wm2_z,
                                     We1_x, We1_z, We2_x, We2_z,
                                     U2h_x, U2h_z, ts_x, ts_z,
                                     BW_x, BW_z, W2_x, W2_z);
    aggA_kernel<<<4096, 256, 0, stream>>>(U2h_x, U2h_z, ts_x, ts_z,
                                          cnt_x, cnt_z, ef_x, ef_z);
    aggB_mfma<<<2048, 256, 0, stream>>>(ts_x, ts_z, h_to_x, h_to_z,
                                        hx_logit, hz_logit,
                                        BW_x, BW_z, W2_x, W2_z, out);
}